// Round 4
// baseline (230.066 us; speedup 1.0000x reference)
//
#include <hip/hip_runtime.h>
#include <hip/hip_bf16.h>
#include <math.h>

#define BATCH 8
#define CI    256
#define HWSZ  1600
#define DDIM  128
#define NHEAD 8
#define DH    16
#define NPTS  32768

typedef __attribute__((ext_vector_type(4))) short s16x4;
typedef __attribute__((ext_vector_type(4))) float f32x4;

#if defined(__HIP_DEVICE_COMPILE__)
  #if __has_builtin(__builtin_amdgcn_mfma_f32_16x16x16bf16_1k)
    #define MFMA16(a, b, c) __builtin_amdgcn_mfma_f32_16x16x16bf16_1k(a, b, c, 0, 0, 0)
  #elif __has_builtin(__builtin_amdgcn_mfma_f32_16x16x16_bf16)
    #define MFMA16(a, b, c) __builtin_amdgcn_mfma_f32_16x16x16_bf16(a, b, c, 0, 0, 0)
  #else
    #error "no 16x16x16 bf16 mfma builtin on this device target"
  #endif
  #if __has_builtin(__builtin_amdgcn_exp2f)
    #define EXP2(x) __builtin_amdgcn_exp2f(x)
  #else
    #define EXP2(x) exp2f(x)
  #endif
#else
  #define MFMA16(a, b, c) (c)
  #define EXP2(x) (x)
#endif

union fragu {
  s16x4 s;
  unsigned int u[2];
  uint2 u2;
};

// packed f32x2 -> bf16x2 (v_cvt_pk_bf16_f32 on gfx950), low = a
__device__ __forceinline__ unsigned int pk_bf2(float a, float b) {
  __hip_bfloat162 h = __float22bfloat162_rn(make_float2(a, b));
  return *(unsigned int*)&h;
}
__device__ __forceinline__ unsigned short f2bf(float x) {
  unsigned int u = __float_as_uint(x);
  return (unsigned short)((u + 0x7FFFu + ((u >> 16) & 1u)) >> 16);
}
__device__ __forceinline__ float bf2f(unsigned short u) {
  return __uint_as_float(((unsigned int)u) << 16);
}

// ---------------- K0: gather W1^T / W2^T into per-lane A-frag layout -----
// W1s[dt][ks][lane] (dt<8, ks<16): A[m=d][k=c], lane: lm=d%16, qd=k-quad:
//   s16x4_i = bf16( W1[(ks*16+4*qd+i)][dt*16+lm] )
// W2s[ct][ks][lane] (ct<16, ks<8): A[m=ci][k=d]:
//   s16x4_i = bf16( W2[(ks*16+4*qd+i)][ct*16+lm] )
__global__ __launch_bounds__(256) void k0_gather(
    const float* __restrict__ W1, const float* __restrict__ W2,
    unsigned short* __restrict__ W1s, unsigned short* __restrict__ W2s) {
  int e = blockIdx.x * 256 + threadIdx.x;     // 16384 entries
  int lane = e & 63, lm = lane & 15, qd = lane >> 4;
  if (e < 8192) {
    int ks = (e >> 6) & 15, dt = e >> 10;
    const float* p = W1 + (size_t)(ks * 16 + 4 * qd) * DDIM + dt * 16 + lm;
    float f0 = p[0], f1 = p[DDIM], f2 = p[2 * DDIM], f3 = p[3 * DDIM];
    *(uint2*)&W1s[(size_t)e * 4] = make_uint2(pk_bf2(f0, f1), pk_bf2(f2, f3));
  } else {
    int e2 = e - 8192;
    int ks = (e2 >> 6) & 7, ct = e2 >> 9;
    const float* p = W2 + (size_t)(ks * 16 + 4 * qd) * CI + ct * 16 + lm;
    float f0 = p[0], f1 = p[CI], f2 = p[2 * CI], f3 = p[3 * CI];
    *(uint2*)&W2s[(size_t)e2 * 4] = make_uint2(pk_bf2(f0, f1), pk_bf2(f2, f3));
  }
}

// ---------------- K1: MFMA linear1 + l2norm -> tokh bf16 [B,8,1600,16] ---
// D[d][tok] = sum_c W1^T[d][c] * img[c][tok].  A = W1s (L2-hot), B = img
// read direct from global (4 strided coalesced floats per k-step), no LDS.
__global__ __launch_bounds__(128) void k1_mfma(
    const float* __restrict__ img, const unsigned short* __restrict__ W1s,
    const float* __restrict__ b1, unsigned short* __restrict__ tokh) {
  int t = threadIdx.x, lane = t & 63, w = t >> 6;
  int lm = lane & 15, qd = lane >> 4;
  int blk = blockIdx.x;                      // 400 = 8b x 50 strips
  int b = blk / 50, n0 = (blk % 50) * 32;
  int tok = n0 + w * 16 + lm;                // B-operand column
  const float* imgb = img + (size_t)b * CI * HWSZ;
  const s16x4* W1s4 = (const s16x4*)W1s;
  f32x4 acc[8];
#pragma unroll
  for (int dt = 0; dt < 8; dt++) acc[dt] = (f32x4){0.f, 0.f, 0.f, 0.f};
#pragma unroll 4
  for (int ks = 0; ks < 16; ks++) {
    const float* p = imgb + (size_t)(ks * 16 + 4 * qd) * HWSZ + tok;
    float f0 = p[0], f1 = p[HWSZ], f2 = p[2 * HWSZ], f3 = p[3 * HWSZ];
    fragu bf_;
    bf_.u[0] = pk_bf2(f0, f1);
    bf_.u[1] = pk_bf2(f2, f3);
#pragma unroll
    for (int dt = 0; dt < 8; dt++) {
      s16x4 af = W1s4[(dt * 16 + ks) * 64 + lane];
      acc[dt] = MFMA16(af, bf_.s, acc[dt]);
    }
  }
  // bias + l2norm over d (this lane holds d = dt*16+4qd+r; quads share token)
  float vals[8][4];
  float ss = 0.f;
#pragma unroll
  for (int dt = 0; dt < 8; dt++)
#pragma unroll
    for (int r = 0; r < 4; r++) {
      float v = acc[dt][r] + b1[dt * 16 + 4 * qd + r];
      vals[dt][r] = v;
      ss += v * v;
    }
  ss += __shfl_xor(ss, 16);
  ss += __shfl_xor(ss, 32);
  float inv = 1.f / fmaxf(sqrtf(ss), 1e-12f);
#pragma unroll
  for (int dt = 0; dt < 8; dt++) {
    uint2 pk = make_uint2(pk_bf2(vals[dt][0] * inv, vals[dt][1] * inv),
                          pk_bf2(vals[dt][2] * inv, vals[dt][3] * inv));
    *(uint2*)&tokh[(((size_t)b * NHEAD + dt) * HWSZ + tok) * DH + 4 * qd] = pk;
  }
}

// ---------------- K2: MFMA flash attention (no-max online softmax) -------
#define NKC      400
#define XK_STR   24
#define VT_STR   408
__global__ __launch_bounds__(256) void k2_attn(
    const unsigned short* __restrict__ tokh, unsigned short* __restrict__ aout) {
  __shared__ unsigned short sXk[NKC * XK_STR];
  __shared__ unsigned short sVt[16 * VT_STR];
  const int bh = blockIdx.x;
  const int b = bh >> 3, h = bh & 7;
  const int t = threadIdx.x;
  const int lane = t & 63;
  const int w = t >> 6;
  const int lm = lane & 15;
  const int qd = lane >> 4;
  const unsigned short* tok = tokh + (size_t)bh * (HWSZ * DH);
  const int qw = blockIdx.y * 256 + w * 64;
  const bool active = qw < HWSZ;

  const float SCL = 0.25f * 1.44269504088896f;
  s16x4 qf[4];
  f32x4 oacc[4];
  float den[4];
  if (active) {
#pragma unroll
    for (int s = 0; s < 4; s++) {
      const unsigned short* qs = tok + (size_t)(qw + s * 16 + lm) * DH + 4 * qd;
      s16x4 raw = *(const s16x4*)qs;
      fragu q;
      q.u[0] = pk_bf2(bf2f((unsigned short)raw[0]) * SCL,
                      bf2f((unsigned short)raw[1]) * SCL);
      q.u[1] = pk_bf2(bf2f((unsigned short)raw[2]) * SCL,
                      bf2f((unsigned short)raw[3]) * SCL);
      qf[s] = q.s;
      oacc[s] = (f32x4){0.f, 0.f, 0.f, 0.f};
      den[s] = 0.f;
    }
  }

  for (int c = 0; c < 4; c++) {
    __syncthreads();
    for (int r = t; r < NKC; r += 256) {
      const uint4* src = (const uint4*)(tok + (size_t)(c * NKC + r) * DH);
      union { uint4 u4[2]; unsigned short us[16]; } uu;
      uu.u4[0] = src[0]; uu.u4[1] = src[1];
      *(uint4*)&sXk[r * XK_STR]     = uu.u4[0];
      *(uint4*)&sXk[r * XK_STR + 8] = uu.u4[1];
#pragma unroll
      for (int d = 0; d < 16; d++) sVt[d * VT_STR + r] = uu.us[d];
    }
    __syncthreads();
    if (active) {
#pragma unroll 1
      for (int st = 0; st < NKC / 16; st++) {
        int n0 = st * 16;
        s16x4 kf = *(const s16x4*)&sXk[(n0 + lm) * XK_STR + 4 * qd];
        s16x4 vf = *(const s16x4*)&sVt[lm * VT_STR + n0 + 4 * qd];
#pragma unroll
        for (int s = 0; s < 4; s++) {
          f32x4 sc = MFMA16(kf, qf[s], ((f32x4){0.f, 0.f, 0.f, 0.f}));
          float e0 = EXP2(sc.x), e1 = EXP2(sc.y), e2 = EXP2(sc.z), e3 = EXP2(sc.w);
          den[s] += (e0 + e1) + (e2 + e3);
          fragu pf;
          pf.u[0] = pk_bf2(e0, e1);
          pf.u[1] = pk_bf2(e2, e3);
          oacc[s] = MFMA16(vf, pf.s, oacc[s]);
        }
      }
    }
  }

  if (active) {
#pragma unroll
    for (int s = 0; s < 4; s++) {
      float d = den[s];
      d += __shfl_xor(d, 16);
      d += __shfl_xor(d, 32);
      float inv = 1.f / d;
      unsigned short* dst = aout + ((size_t)b * HWSZ + qw + s * 16 + lm) * DDIM
                            + h * DH + 4 * qd;
      *(uint2*)dst = make_uint2(pk_bf2(oacc[s].x * inv, oacc[s].y * inv),
                                pk_bf2(oacc[s].z * inv, oacc[s].w * inv));
    }
  }
}

// ---------------- K3: MFMA linear2 -> img_out [B,256,1600] ---------------
// D[ci][tok] = sum_d W2^T[ci][d] * aout^T[d][tok].  A = W2s (L2-hot),
// B = aout bf16 read direct (natural layout), no LDS.
__global__ __launch_bounds__(128) void k3_mfma(
    const unsigned short* __restrict__ aout, const unsigned short* __restrict__ W2s,
    const float* __restrict__ b2, float* __restrict__ img_out) {
  int t = threadIdx.x, lane = t & 63, w = t >> 6;
  int lm = lane & 15, qd = lane >> 4;
  int blk = blockIdx.x;                      // 400 = 8b x 50 strips
  int b = blk / 50, n0 = (blk % 50) * 32;
  int tok = n0 + w * 16 + lm;
  const unsigned short* arow = aout + ((size_t)b * HWSZ + tok) * DDIM;
  const s16x4* W2s4 = (const s16x4*)W2s;
  f32x4 acc[16];
#pragma unroll
  for (int ct = 0; ct < 16; ct++) acc[ct] = (f32x4){0.f, 0.f, 0.f, 0.f};
#pragma unroll 2
  for (int ks = 0; ks < 8; ks++) {
    s16x4 bf_ = *(const s16x4*)(arow + ks * 16 + 4 * qd);
#pragma unroll
    for (int ct = 0; ct < 16; ct++) {
      s16x4 af = W2s4[(ct * 8 + ks) * 64 + lane];
      acc[ct] = MFMA16(af, bf_, acc[ct]);
    }
  }
  float* ob = img_out + (size_t)b * CI * HWSZ;
#pragma unroll
  for (int ct = 0; ct < 16; ct++)
#pragma unroll
    for (int r = 0; r < 4; r++) {
      int ci = ct * 16 + 4 * qd + r;
      ob[(size_t)ci * HWSZ + tok] = acc[ct][r] + b2[ci];
    }
}

// ---------------- K3b: image GeM (coalesced row reduction) ---------------
__global__ __launch_bounds__(256) void k3b_imgem(
    const float* __restrict__ img_out, float* __restrict__ image_gem) {
  int w = threadIdx.x >> 6, lane = threadIdx.x & 63;
  int row = blockIdx.x * 4 + w;              // 2048 rows of 1600
  const float* r = img_out + (size_t)row * HWSZ;
  float s = 0.f;
  for (int i = lane; i < HWSZ; i += 64) {
    float c = fmaxf(r[i], 1e-6f);
    s += c * c * c;
  }
  s += __shfl_xor(s, 1);  s += __shfl_xor(s, 2);  s += __shfl_xor(s, 4);
  s += __shfl_xor(s, 8);  s += __shfl_xor(s, 16); s += __shfl_xor(s, 32);
  if (lane == 0) image_gem[row] = powf(s * (1.f / (float)HWSZ), 1.f / 3.f);
}

// ---------------- K4: cloud l2norm + segment GeM partials ----------------
__global__ __launch_bounds__(256) void k4_cloud(
    const float* __restrict__ cf, const int* __restrict__ bids,
    float* __restrict__ cloud_out, float* __restrict__ cacc,
    float* __restrict__ cnt) {
  __shared__ float ga[BATCH * DDIM];
  __shared__ float gc[BATCH];
  int t = threadIdx.x;
  for (int i = t; i < BATCH * DDIM; i += 256) ga[i] = 0.f;
  if (t < BATCH) gc[t] = 0.f;
  __syncthreads();
  int r = blockIdx.x * 64 + (t >> 2);
  int dq = (t & 3) * 32;
  const float* row = cf + (size_t)r * DDIM + dq;
  float4 v[8];
  float ss = 0.f;
#pragma unroll
  for (int j = 0; j < 8; j++) {
    v[j] = *(const float4*)(row + j * 4);
    ss += v[j].x*v[j].x + v[j].y*v[j].y + v[j].z*v[j].z + v[j].w*v[j].w;
  }
  ss += __shfl_xor(ss, 1);
  ss += __shfl_xor(ss, 2);
  float sc = 1.f / fmaxf(sqrtf(ss), 1e-12f);
  int bid = bids[r];
  if ((t & 3) == 0) atomicAdd(&gc[bid], 1.f);
  float* orow = cloud_out + (size_t)r * DDIM + dq;
  float* gb = &ga[bid * DDIM + dq];
#pragma unroll
  for (int j = 0; j < 8; j++) {
    float4 y;
    y.x = v[j].x * sc; y.y = v[j].y * sc; y.z = v[j].z * sc; y.w = v[j].w * sc;
    *(float4*)(orow + j * 4) = y;
    float c0 = fmaxf(y.x, 1e-6f), c1 = fmaxf(y.y, 1e-6f);
    float c2 = fmaxf(y.z, 1e-6f), c3 = fmaxf(y.w, 1e-6f);
    atomicAdd(&gb[j*4+0], c0*c0*c0);
    atomicAdd(&gb[j*4+1], c1*c1*c1);
    atomicAdd(&gb[j*4+2], c2*c2*c2);
    atomicAdd(&gb[j*4+3], c3*c3*c3);
  }
  __syncthreads();
  for (int i = t; i < BATCH * DDIM; i += 256) atomicAdd(&cacc[i], ga[i]);
  if (t < BATCH) atomicAdd(&cnt[t], gc[t]);
}

// ---------------- K5: finalize cloud GeM ---------------------------------
__global__ __launch_bounds__(256) void k5_final(
    const float* __restrict__ cacc, const float* __restrict__ cnt,
    float* __restrict__ cloud_gem) {
  int j = blockIdx.x * 256 + threadIdx.x;
  if (j < BATCH * DDIM) {
    int b = j >> 7;
    cloud_gem[j] = powf(cacc[j] / fmaxf(cnt[b], 1.f), 1.f / 3.f);
  }
}

extern "C" void kernel_launch(void* const* d_in, const int* in_sizes, int n_in,
                              void* d_out, int out_size, void* d_ws, size_t ws_size,
                              hipStream_t stream) {
  const float* image_feat = (const float*)d_in[0];
  const float* cloud_feat = (const float*)d_in[1];
  const int*   cloud_bids = (const int*)d_in[2];
  const float* W1 = (const float*)d_in[3];
  const float* b1 = (const float*)d_in[4];
  const float* W2 = (const float*)d_in[5];
  const float* b2 = (const float*)d_in[6];

  float* out = (float*)d_out;
  float* img_out   = out;                                  // [8,256,40,40]
  float* cloud_out = out + 3276800;                        // [32768,128]
  float* image_gem = out + 3276800 + 4194304;              // [8,256]
  float* cloud_gem = image_gem + 2048;                     // [8,128]

  char* ws = (char*)d_ws;
  unsigned short* tokh = (unsigned short*)ws;              // bf16 [8,8,1600,16]  3,276,800 B
  unsigned short* aout = (unsigned short*)(ws + 3276800);  // bf16 [8,1600,128]   3,276,800 B
  unsigned short* W1s  = (unsigned short*)(ws + 6553600);  // 65,536 B
  unsigned short* W2s  = (unsigned short*)(ws + 6619136);  // 65,536 B
  float* cacc = (float*)(ws + 6684672);                    // [8,128]
  float* cnt  = cacc + 1024;                               // [8]

  (void)hipMemsetAsync(cacc, 0, (1024 + 8) * sizeof(float), stream);

  k0_gather<<<dim3(64), dim3(256), 0, stream>>>(W1, W2, W1s, W2s);
  k1_mfma<<<dim3(400), dim3(128), 0, stream>>>(image_feat, W1s, b1, tokh);
  k2_attn<<<dim3(64, 7), dim3(256), 0, stream>>>(tokh, aout);
  k3_mfma<<<dim3(400), dim3(128), 0, stream>>>(aout, W2s, b2, img_out);
  k3b_imgem<<<dim3(512), dim3(256), 0, stream>>>(img_out, image_gem);
  k4_cloud<<<dim3(512), dim3(256), 0, stream>>>(cloud_feat, cloud_bids,
                                                cloud_out, cacc, cnt);
  k5_final<<<dim3(4), dim3(256), 0, stream>>>(cacc, cnt, cloud_gem);
}

// Round 5
// 206.755 us; speedup vs baseline: 1.1127x; 1.1127x over previous
//
#include <hip/hip_runtime.h>
#include <hip/hip_bf16.h>
#include <math.h>

#define BATCH 8
#define CI    256
#define HWSZ  1600
#define DDIM  128
#define NHEAD 8
#define DH    16
#define NPTS  32768

typedef __attribute__((ext_vector_type(4))) short s16x4;
typedef __attribute__((ext_vector_type(4))) float f32x4;

#if defined(__HIP_DEVICE_COMPILE__)
  #if __has_builtin(__builtin_amdgcn_mfma_f32_16x16x16bf16_1k)
    #define MFMA16(a, b, c) __builtin_amdgcn_mfma_f32_16x16x16bf16_1k(a, b, c, 0, 0, 0)
  #elif __has_builtin(__builtin_amdgcn_mfma_f32_16x16x16_bf16)
    #define MFMA16(a, b, c) __builtin_amdgcn_mfma_f32_16x16x16_bf16(a, b, c, 0, 0, 0)
  #else
    #error "no 16x16x16 bf16 mfma builtin on this device target"
  #endif
  #if __has_builtin(__builtin_amdgcn_exp2f)
    #define EXP2(x) __builtin_amdgcn_exp2f(x)
  #else
    #define EXP2(x) exp2f(x)
  #endif
#else
  #define MFMA16(a, b, c) (c)
  #define EXP2(x) (x)
#endif

union fragu {
  s16x4 s;
  unsigned int u[2];
  uint2 u2;
};

__device__ __forceinline__ unsigned int pk_bf2(float a, float b) {
  __hip_bfloat162 h = __float22bfloat162_rn(make_float2(a, b));
  return *(unsigned int*)&h;
}
__device__ __forceinline__ float bf2f(unsigned short u) {
  return __uint_as_float(((unsigned int)u) << 16);
}

// ---------------- KPREP: blocks 0..63 = weight gather; 64..319 = cloud ---
// W1s[dt][ks][lane]: A-frag bf16 of W1^T; W2s[ct][ks][lane]: A-frag of W2^T.
// Cloud part: l2norm rows + per-block GeM partials (write-once, no atomics
// to global, no zero-init dependency).
__global__ __launch_bounds__(256) void kprep(
    const float* __restrict__ W1, const float* __restrict__ W2,
    const float* __restrict__ cf, const int* __restrict__ bids,
    unsigned short* __restrict__ W1s, unsigned short* __restrict__ W2s,
    float* __restrict__ cloud_out, float* __restrict__ gaw,
    float* __restrict__ cntw) {
  __shared__ float ga[BATCH * DDIM];
  __shared__ float gc[BATCH];
  int t = threadIdx.x;
  if (blockIdx.x < 64) {
    int e = blockIdx.x * 256 + t;             // 16384 entries
    int lane = e & 63, lm = lane & 15, qd = lane >> 4;
    if (e < 8192) {
      int ks = (e >> 6) & 15, dt = e >> 10;
      const float* p = W1 + (size_t)(ks * 16 + 4 * qd) * DDIM + dt * 16 + lm;
      float f0 = p[0], f1 = p[DDIM], f2 = p[2 * DDIM], f3 = p[3 * DDIM];
      *(uint2*)&W1s[(size_t)e * 4] = make_uint2(pk_bf2(f0, f1), pk_bf2(f2, f3));
    } else {
      int e2 = e - 8192;
      int ks = (e2 >> 6) & 7, ct = e2 >> 9;
      const float* p = W2 + (size_t)(ks * 16 + 4 * qd) * CI + ct * 16 + lm;
      float f0 = p[0], f1 = p[CI], f2 = p[2 * CI], f3 = p[3 * CI];
      *(uint2*)&W2s[(size_t)e2 * 4] = make_uint2(pk_bf2(f0, f1), pk_bf2(f2, f3));
    }
    return;
  }
  int bk = blockIdx.x - 64;                   // 0..255, 128 rows each
  for (int i = t; i < BATCH * DDIM; i += 256) ga[i] = 0.f;
  if (t < BATCH) gc[t] = 0.f;
  __syncthreads();
  for (int half = 0; half < 2; half++) {
    int r = bk * 128 + half * 64 + (t >> 2);
    int dq = (t & 3) * 32;
    const float* row = cf + (size_t)r * DDIM + dq;
    float4 v[8];
    float ss = 0.f;
#pragma unroll
    for (int j = 0; j < 8; j++) {
      v[j] = *(const float4*)(row + j * 4);
      ss += v[j].x*v[j].x + v[j].y*v[j].y + v[j].z*v[j].z + v[j].w*v[j].w;
    }
    ss += __shfl_xor(ss, 1);
    ss += __shfl_xor(ss, 2);
    float sc = 1.f / fmaxf(sqrtf(ss), 1e-12f);
    int bid = bids[r];
    if ((t & 3) == 0) atomicAdd(&gc[bid], 1.f);
    float* orow = cloud_out + (size_t)r * DDIM + dq;
    float* gb = &ga[bid * DDIM + dq];
#pragma unroll
    for (int j = 0; j < 8; j++) {
      float4 y;
      y.x = v[j].x * sc; y.y = v[j].y * sc; y.z = v[j].z * sc; y.w = v[j].w * sc;
      *(float4*)(orow + j * 4) = y;
      float c0 = fmaxf(y.x, 1e-6f), c1 = fmaxf(y.y, 1e-6f);
      float c2 = fmaxf(y.z, 1e-6f), c3 = fmaxf(y.w, 1e-6f);
      atomicAdd(&gb[j*4+0], c0*c0*c0);
      atomicAdd(&gb[j*4+1], c1*c1*c1);
      atomicAdd(&gb[j*4+2], c2*c2*c2);
      atomicAdd(&gb[j*4+3], c3*c3*c3);
    }
  }
  __syncthreads();
  for (int i = t; i < BATCH * DDIM; i += 256) gaw[(size_t)bk * 1024 + i] = ga[i];
  if (t < BATCH) cntw[bk * 8 + t] = gc[t];
}

// ---------------- K1: MFMA linear1 + l2norm -> tokh bf16 [B,8,1600,16] ---
// 4 waves/block, full B-prefetch (64 loads) before the MFMA chain so HBM
// latency is paid once per wave, not per k-step.
__global__ __launch_bounds__(256) void k1_mfma(
    const float* __restrict__ img, const unsigned short* __restrict__ W1s,
    const float* __restrict__ b1, unsigned short* __restrict__ tokh) {
  int t = threadIdx.x, lane = t & 63, w = t >> 6;
  int lm = lane & 15, qd = lane >> 4;
  int blk = blockIdx.x;                      // 200 = 8b x 25 strips of 64
  int b = blk / 25, n0 = (blk % 25) * 64;
  int tok = n0 + w * 16 + lm;
  const float* imgb = img + (size_t)b * CI * HWSZ;
  const s16x4* W1s4 = (const s16x4*)W1s;
  float fv[16][4];
#pragma unroll
  for (int ks = 0; ks < 16; ks++) {
    const float* p = imgb + (size_t)(ks * 16 + 4 * qd) * HWSZ + tok;
    fv[ks][0] = p[0];        fv[ks][1] = p[HWSZ];
    fv[ks][2] = p[2 * HWSZ]; fv[ks][3] = p[3 * HWSZ];
  }
  f32x4 acc[8];
#pragma unroll
  for (int dt = 0; dt < 8; dt++) acc[dt] = (f32x4){0.f, 0.f, 0.f, 0.f};
#pragma unroll
  for (int ks = 0; ks < 16; ks++) {
    fragu bf_;
    bf_.u[0] = pk_bf2(fv[ks][0], fv[ks][1]);
    bf_.u[1] = pk_bf2(fv[ks][2], fv[ks][3]);
#pragma unroll
    for (int dt = 0; dt < 8; dt++) {
      s16x4 af = W1s4[(dt * 16 + ks) * 64 + lane];
      acc[dt] = MFMA16(af, bf_.s, acc[dt]);
    }
  }
  float vals[8][4];
  float ss = 0.f;
#pragma unroll
  for (int dt = 0; dt < 8; dt++)
#pragma unroll
    for (int r = 0; r < 4; r++) {
      float v = acc[dt][r] + b1[dt * 16 + 4 * qd + r];
      vals[dt][r] = v;
      ss += v * v;
    }
  ss += __shfl_xor(ss, 16);
  ss += __shfl_xor(ss, 32);
  float inv = 1.f / fmaxf(sqrtf(ss), 1e-12f);
#pragma unroll
  for (int dt = 0; dt < 8; dt++) {
    uint2 pk = make_uint2(pk_bf2(vals[dt][0] * inv, vals[dt][1] * inv),
                          pk_bf2(vals[dt][2] * inv, vals[dt][3] * inv));
    *(uint2*)&tokh[(((size_t)b * NHEAD + dt) * HWSZ + tok) * DH + 4 * qd] = pk;
  }
}

// ---------------- K2: MFMA flash attention, key-split 2x -----------------
// grid (128,7): x = bh*2 + kc; each block handles 800 keys (2 chunks of
// 400) and writes UNNORMALIZED (num, den) partials; k3 combines.
#define NKC      400
#define XK_STR   24
#define VT_STR   408
__global__ __launch_bounds__(256) void k2_attn(
    const unsigned short* __restrict__ tokh, float* __restrict__ numw,
    float* __restrict__ denw) {
  __shared__ unsigned short sXk[NKC * XK_STR];
  __shared__ unsigned short sVt[16 * VT_STR];
  const int gx = blockIdx.x;
  const int bh = gx >> 1, kc = gx & 1;
  const int t = threadIdx.x;
  const int lane = t & 63;
  const int w = t >> 6;
  const int lm = lane & 15;
  const int qd = lane >> 4;
  const unsigned short* tok = tokh + (size_t)bh * (HWSZ * DH);
  const int qw = blockIdx.y * 256 + w * 64;
  const bool active = qw < HWSZ;

  const float SCL = 0.25f * 1.44269504088896f;
  s16x4 qf[4];
  f32x4 oacc[4];
  float den[4];
  if (active) {
#pragma unroll
    for (int s = 0; s < 4; s++) {
      const unsigned short* qs = tok + (size_t)(qw + s * 16 + lm) * DH + 4 * qd;
      s16x4 raw = *(const s16x4*)qs;
      fragu q;
      q.u[0] = pk_bf2(bf2f((unsigned short)raw[0]) * SCL,
                      bf2f((unsigned short)raw[1]) * SCL);
      q.u[1] = pk_bf2(bf2f((unsigned short)raw[2]) * SCL,
                      bf2f((unsigned short)raw[3]) * SCL);
      qf[s] = q.s;
      oacc[s] = (f32x4){0.f, 0.f, 0.f, 0.f};
      den[s] = 0.f;
    }
  }

  for (int cc = 0; cc < 2; cc++) {
    int c = kc * 2 + cc;
    __syncthreads();
    for (int r = t; r < NKC; r += 256) {
      const uint4* src = (const uint4*)(tok + (size_t)(c * NKC + r) * DH);
      union { uint4 u4[2]; unsigned short us[16]; } uu;
      uu.u4[0] = src[0]; uu.u4[1] = src[1];
      *(uint4*)&sXk[r * XK_STR]     = uu.u4[0];
      *(uint4*)&sXk[r * XK_STR + 8] = uu.u4[1];
#pragma unroll
      for (int d = 0; d < 16; d++) sVt[d * VT_STR + r] = uu.us[d];
    }
    __syncthreads();
    if (active) {
#pragma unroll 1
      for (int st = 0; st < NKC / 16; st++) {
        int n0 = st * 16;
        s16x4 kf = *(const s16x4*)&sXk[(n0 + lm) * XK_STR + 4 * qd];
        s16x4 vf = *(const s16x4*)&sVt[lm * VT_STR + n0 + 4 * qd];
#pragma unroll
        for (int s = 0; s < 4; s++) {
          f32x4 sc = MFMA16(kf, qf[s], ((f32x4){0.f, 0.f, 0.f, 0.f}));
          float e0 = EXP2(sc.x), e1 = EXP2(sc.y), e2 = EXP2(sc.z), e3 = EXP2(sc.w);
          den[s] += (e0 + e1) + (e2 + e3);
          fragu pf;
          pf.u[0] = pk_bf2(e0, e1);
          pf.u[1] = pk_bf2(e2, e3);
          oacc[s] = MFMA16(vf, pf.s, oacc[s]);
        }
      }
    }
  }

  if (active) {
#pragma unroll
    for (int s = 0; s < 4; s++) {
      float d = den[s];
      d += __shfl_xor(d, 16);
      d += __shfl_xor(d, 32);
      size_t q = (size_t)qw + s * 16 + lm;
      float* np = numw + (((size_t)bh * 2 + kc) * HWSZ + q) * 16 + 4 * qd;
      *(f32x4*)np = oacc[s];
      if (qd == 0) denw[((size_t)bh * 2 + kc) * HWSZ + q] = d;
    }
  }
}

// ---------------- K3: combine attn partials + MFMA linear2 ---------------
// B-frag (ks, qd) spans head h = ks, dims 4qd..4qd+3: combine the 2 key-
// split partials ((n0+n1)/(d0+d1)) in-register, then 16 MFMAs per ks.
__global__ __launch_bounds__(256) void k3_mfma(
    const float* __restrict__ numw, const float* __restrict__ denw,
    const unsigned short* __restrict__ W2s, const float* __restrict__ b2,
    float* __restrict__ img_out) {
  int t = threadIdx.x, lane = t & 63, w = t >> 6;
  int lm = lane & 15, qd = lane >> 4;
  int blk = blockIdx.x;                      // 200 = 8b x 25 strips of 64
  int b = blk / 25, n0 = (blk % 25) * 64;
  int tok = n0 + w * 16 + lm;
  const s16x4* W2s4 = (const s16x4*)W2s;
  f32x4 acc[16];
#pragma unroll
  for (int ct = 0; ct < 16; ct++) acc[ct] = (f32x4){0.f, 0.f, 0.f, 0.f};
#pragma unroll 2
  for (int ks = 0; ks < 8; ks++) {
    size_t bh2 = (size_t)(b * 8 + ks) * 2;
    const float* npb = numw + (bh2 * HWSZ + tok) * 16 + 4 * qd;
    f32x4 nv0 = *(const f32x4*)npb;
    f32x4 nv1 = *(const f32x4*)(npb + (size_t)HWSZ * 16);
    float d0 = denw[bh2 * HWSZ + tok];
    float d1 = denw[bh2 * HWSZ + HWSZ + tok];
    float inv = 1.f / (d0 + d1);
    fragu bf_;
    bf_.u[0] = pk_bf2((nv0.x + nv1.x) * inv, (nv0.y + nv1.y) * inv);
    bf_.u[1] = pk_bf2((nv0.z + nv1.z) * inv, (nv0.w + nv1.w) * inv);
#pragma unroll
    for (int ct = 0; ct < 16; ct++) {
      s16x4 af = W2s4[(ct * 8 + ks) * 64 + lane];
      acc[ct] = MFMA16(af, bf_.s, acc[ct]);
    }
  }
  float* ob = img_out + (size_t)b * CI * HWSZ;
#pragma unroll
  for (int ct = 0; ct < 16; ct++)
#pragma unroll
    for (int r = 0; r < 4; r++) {
      int ci = ct * 16 + 4 * qd + r;
      ob[(size_t)ci * HWSZ + tok] = acc[ct][r] + b2[ci];
    }
}

// ---------------- KPOST: image GeM rows + cloud GeM combine --------------
__global__ __launch_bounds__(256) void kpost(
    const float* __restrict__ img_out, const float* __restrict__ gaw,
    const float* __restrict__ cntw, float* __restrict__ image_gem,
    float* __restrict__ cloud_gem) {
  __shared__ float cs[BATCH];
  int t = threadIdx.x;
  if (blockIdx.x < 512) {
    int w = t >> 6, lane = t & 63;
    int row = blockIdx.x * 4 + w;            // 2048 rows of 1600
    const float* r = img_out + (size_t)row * HWSZ;
    float s = 0.f;
    for (int i = lane; i < HWSZ; i += 64) {
      float c = fmaxf(r[i], 1e-6f);
      s += c * c * c;
    }
    s += __shfl_xor(s, 1);  s += __shfl_xor(s, 2);  s += __shfl_xor(s, 4);
    s += __shfl_xor(s, 8);  s += __shfl_xor(s, 16); s += __shfl_xor(s, 32);
    if (lane == 0) image_gem[row] = powf(s * (1.f / (float)HWSZ), 1.f / 3.f);
  } else {
    int j = (blockIdx.x - 512) * 256 + t;    // 0..1023
    if (t < BATCH) {
      float s = 0.f;
      for (int k = 0; k < 256; k++) s += cntw[k * 8 + t];
      cs[t] = s;
    }
    __syncthreads();
    float s = 0.f;
#pragma unroll 4
    for (int k = 0; k < 256; k++) s += gaw[(size_t)k * 1024 + j];
    int b = j >> 7;
    cloud_gem[j] = powf(s / fmaxf(cs[b], 1.f), 1.f / 3.f);
  }
}

extern "C" void kernel_launch(void* const* d_in, const int* in_sizes, int n_in,
                              void* d_out, int out_size, void* d_ws, size_t ws_size,
                              hipStream_t stream) {
  const float* image_feat = (const float*)d_in[0];
  const float* cloud_feat = (const float*)d_in[1];
  const int*   cloud_bids = (const int*)d_in[2];
  const float* W1 = (const float*)d_in[3];
  const float* b1 = (const float*)d_in[4];
  const float* W2 = (const float*)d_in[5];
  const float* b2 = (const float*)d_in[6];

  float* out = (float*)d_out;
  float* img_out   = out;                                  // [8,256,40,40]
  float* cloud_out = out + 3276800;                        // [32768,128]
  float* image_gem = out + 3276800 + 4194304;              // [8,256]
  float* cloud_gem = image_gem + 2048;                     // [8,128]

  char* ws = (char*)d_ws;
  unsigned short* tokh = (unsigned short*)ws;              // 3,276,800 B
  float* numw = (float*)(ws + 3276800);                    // 13,107,200 B
  float* denw = (float*)(ws + 16384000);                   //    819,200 B
  unsigned short* W1s = (unsigned short*)(ws + 17203200);  //     65,536 B
  unsigned short* W2s = (unsigned short*)(ws + 17268736);  //     65,536 B
  float* gaw  = (float*)(ws + 17334272);                   //  1,048,576 B
  float* cntw = (float*)(ws + 18382848);                   //      8,192 B

  kprep<<<dim3(320), dim3(256), 0, stream>>>(W1, W2, cloud_feat, cloud_bids,
                                             W1s, W2s, cloud_out, gaw, cntw);
  k1_mfma<<<dim3(200), dim3(256), 0, stream>>>(image_feat, W1s, b1, tokh);
  k2_attn<<<dim3(128, 7), dim3(256), 0, stream>>>(tokh, numw, denw);
  k3_mfma<<<dim3(200), dim3(256), 0, stream>>>(numw, denw, W2s, b2, img_out);
  kpost<<<dim3(516), dim3(256), 0, stream>>>(img_out, gaw, cntw,
                                             image_gem, cloud_gem);
}